// Round 10
// baseline (231.150 us; speedup 1.0000x reference)
//
#include <hip/hip_runtime.h>
#include <math.h>

#define T_STEPS 256
#define BATCH   2048
#define HID     10

#define S2P  2.8853900817779268f   // 2/ln2
#define SNP -1.4426950408889634f   // -1/ln2
#define LN2  0.6931471805599453f
#define LOGPI 1.1447298858494002f

typedef float v2f __attribute__((ext_vector_type(2)));

__device__ __forceinline__ float frcp(float x){ return __builtin_amdgcn_rcpf(x); }
__device__ __forceinline__ float ex2 (float x){ return __builtin_amdgcn_exp2f(x); }
__device__ __forceinline__ float ftanh2(float y){ return 1.f - 2.f*frcp(1.f + ex2(y)); }
__device__ __forceinline__ float fsigm2(float y){ return frcp(1.f + ex2(y)); }

// DPP row rotate-right by K within each 16-lane row: result[lane j] = src[(j-K)&15]
template<int K> __device__ __forceinline__ float rotk(float x){
  return __int_as_float(__builtin_amdgcn_update_dpp(
      0, __float_as_int(x), 0x120 + K, 0xF, 0xF, false));
}
#define ROT16(r, v) do{ float _v=(v); r[0]=_v; \
  r[1]=rotk<1>(_v);  r[2]=rotk<2>(_v);  r[3]=rotk<3>(_v);  r[4]=rotk<4>(_v);  \
  r[5]=rotk<5>(_v);  r[6]=rotk<6>(_v);  r[7]=rotk<7>(_v);  r[8]=rotk<8>(_v);  \
  r[9]=rotk<9>(_v);  r[10]=rotk<10>(_v);r[11]=rotk<11>(_v);r[12]=rotk<12>(_v);\
  r[13]=rotk<13>(_v);r[14]=rotk<14>(_v);r[15]=rotk<15>(_v); }while(0)

// rotate a PAIR {a,b} together (pre-paired for pk_fma)
#define ROTP(r, a, b) do{ float _a=(a), _b=(b); r[0]=(v2f){_a,_b}; \
  r[1]=(v2f){rotk<1>(_a),rotk<1>(_b)};   r[2]=(v2f){rotk<2>(_a),rotk<2>(_b)}; \
  r[3]=(v2f){rotk<3>(_a),rotk<3>(_b)};   r[4]=(v2f){rotk<4>(_a),rotk<4>(_b)}; \
  r[5]=(v2f){rotk<5>(_a),rotk<5>(_b)};   r[6]=(v2f){rotk<6>(_a),rotk<6>(_b)}; \
  r[7]=(v2f){rotk<7>(_a),rotk<7>(_b)};   r[8]=(v2f){rotk<8>(_a),rotk<8>(_b)}; \
  r[9]=(v2f){rotk<9>(_a),rotk<9>(_b)};   r[10]=(v2f){rotk<10>(_a),rotk<10>(_b)}; \
  r[11]=(v2f){rotk<11>(_a),rotk<11>(_b)};r[12]=(v2f){rotk<12>(_a),rotk<12>(_b)}; \
  r[13]=(v2f){rotk<13>(_a),rotk<13>(_b)};r[14]=(v2f){rotk<14>(_a),rotk<14>(_b)}; \
  r[15]=(v2f){rotk<15>(_a),rotk<15>(_b)}; }while(0)

__device__ __forceinline__ float dot16(const float* r, const float* w, float bias){
  float a0 = fmaf(r[0], w[0], bias);
  float a1 = r[1]*w[1];
  float a2 = r[2]*w[2];
  float a3 = r[3]*w[3];
  #pragma unroll
  for (int k=4;k<16;k+=4){
    a0 = fmaf(r[k  ], w[k  ], a0);
    a1 = fmaf(r[k+1], w[k+1], a1);
    a2 = fmaf(r[k+2], w[k+2], a2);
    a3 = fmaf(r[k+3], w[k+3], a3);
  }
  return (a0+a1)+(a2+a3);
}
__device__ __forceinline__ v2f dotp16(const v2f* r, const v2f* w, v2f init){
  v2f a0 = __builtin_elementwise_fma(r[0], w[0], init);
  v2f a1 = r[1]*w[1];
  v2f a2 = r[2]*w[2];
  v2f a3 = r[3]*w[3];
  #pragma unroll
  for (int k=4;k<16;k+=4){
    a0 = __builtin_elementwise_fma(r[k  ], w[k  ], a0);
    a1 = __builtin_elementwise_fma(r[k+1], w[k+1], a1);
    a2 = __builtin_elementwise_fma(r[k+2], w[k+2], a2);
    a3 = __builtin_elementwise_fma(r[k+3], w[k+3], a3);
  }
  return (a0+a1)+(a2+a3);
}
__device__ __forceinline__ float dot16x(const float* r, const v2f* w, float bias){
  float a0 = fmaf(r[0], w[0].x, bias);
  float a1 = r[1]*w[1].x;
  float a2 = r[2]*w[2].x;
  float a3 = r[3]*w[3].x;
  #pragma unroll
  for (int k=4;k<16;k+=4){
    a0 = fmaf(r[k  ], w[k  ].x, a0);
    a1 = fmaf(r[k+1], w[k+1].x, a1);
    a2 = fmaf(r[k+2], w[k+2].x, a2);
    a3 = fmaf(r[k+3], w[k+3].x, a3);
  }
  return (a0+a1)+(a2+a3);
}
// scalar dot against the .y halves of packed rez (= rotated z)
__device__ __forceinline__ float dot16y(const v2f* r, const float* w, float bias){
  float a0 = fmaf(r[0].y, w[0], bias);
  float a1 = r[1].y*w[1];
  float a2 = r[2].y*w[2];
  float a3 = r[3].y*w[3];
  #pragma unroll
  for (int k=4;k<16;k+=4){
    a0 = fmaf(r[k  ].y, w[k  ], a0);
    a1 = fmaf(r[k+1].y, w[k+1], a1);
    a2 = fmaf(r[k+2].y, w[k+2], a2);
    a3 = fmaf(r[k+3].y, w[k+3], a3);
  }
  return (a0+a1)+(a2+a3);
}

template<int NROW, int NCOL>
__device__ __forceinline__ void loadrot(float* dst, const float* W, int j, int col,
                                        bool colok, float scale){
  int colc = colok ? col : 0;
  #pragma unroll
  for (int k=0;k<16;k++){
    int i = (j - k) & 15;
    bool v = colok && (i < NROW);
    int ic = v ? i : 0;
    float w = W[ic*NCOL + colc];
    dst[k] = v ? scale*w : 0.f;
  }
}
__device__ __forceinline__ float bload(const float* p, int idx, bool ok, float scale){
  float t = p[ok ? idx : 0];
  return ok ? scale*t : 0.f;
}
template<int X> __device__ __forceinline__ float xor16(float x){
  return __int_as_float(__builtin_amdgcn_ds_swizzle(__float_as_int(x), (X<<10)|0x1f));
}

struct P34 { const float* p[34]; float* ws; float* out; };

// ======= single fused kernel: recurrence + generator + KLD + GLL + loss, no workspace =======
__global__ __attribute__((amdgpu_flat_work_group_size(64, 64), amdgpu_waves_per_eu(1, 1)))
void k1_fused(P34 prm)
{
  const int tid = threadIdx.x;
  const int j   = tid & 15;
  const int grp = tid >> 4;
  const int b   = blockIdx.x*4 + grp;
  const bool act = (j < HID);
  const int  jl  = act ? j : 0;

  const float* __restrict__ seq   = prm.p[0];
  const float* __restrict__ noise = prm.p[1];
  float* __restrict__ out = prm.out;

  // ---- inference weights (packed as round 9) ----
  float w_ii0   = bload(prm.p[10],      jl, act, S2P);
  float w_ii1   = bload(prm.p[10], 10 + jl, act, S2P);
  float b_in_in = bload(prm.p[11], jl, act, S2P);
  float tje[16], tjz[16], tmu[16], tsg[16], w_h[16];
  loadrot<10,10>(tje, prm.p[12],       j, j, act, S2P);
  loadrot<10,10>(tjz, prm.p[12] + 100, j, j, act, S2P);
  loadrot<10,10>(w_h, prm.p[14],       j, j, act, S2P);
  loadrot<10,10>(tmu, prm.p[16],       j, j, act, S2P);
  loadrot<10,10>(tsg, prm.p[18],       j, j, act, SNP);
  v2f wez[16], wmsg[16];
  #pragma unroll
  for (int k=0;k<16;k++){ wez[k]=(v2f){tje[k],tjz[k]}; wmsg[k]=(v2f){tmu[k],tsg[k]}; }
  float b_in_j  = bload(prm.p[13], jl, act, S2P);
  float b_in_h  = bload(prm.p[15], jl, act, S2P);
  float b_in_mu = bload(prm.p[17], jl, act, S2P);
  float b_in_sg = bload(prm.p[19], jl, act, SNP);
  const v2f bmsg = (v2f){b_in_mu, b_in_sg};

  // ---- transition weights ----
  float wth[16];  loadrot<10,10>(wth,  prm.p[20], j, j, act, S2P);
  float bth  = bload(prm.p[21], jl, act, S2P);
  float wtmu[16]; loadrot<10,10>(wtmu, prm.p[22], j, j, act, S2P);
  float btmu = bload(prm.p[23], jl, act, S2P);
  float wtsg[16]; loadrot<10,10>(wtsg, prm.p[24], j, j, act, S2P);
  float btsg = bload(prm.p[25], jl, act, S2P);

  // ---- generator weights (relu layers unscaled; output head sigmoid-scaled) ----
  float wg1[16]; loadrot<10,10>(wg1, prm.p[26], j, j, act, 1.f);
  float bg1 = bload(prm.p[27], jl, act, 1.f);
  float wg2[16]; loadrot<10,10>(wg2, prm.p[28], j, j, act, 1.f);
  float bg2 = bload(prm.p[29], jl, act, 1.f);
  const bool isd = (j < 4);                 // lanes 0,1: mu cols; 2,3: sg cols
  const float* Wgo = (j < 2) ? prm.p[30] : prm.p[32];
  const float* Bgo = (j < 2) ? prm.p[31] : prm.p[33];
  float wgo[16]; loadrot<10,2>(wgo, Wgo, j, j & 1, isd, SNP);
  float bgo = bload(Bgo, j & 1, isd, SNP);

  float LL = 0.f;   // linear loss accumulator (contributes +ΣA −ΣB linear parts)
  float L2 = 0.f;   // log2 accumulator (scaled by ln2 at the end)

  auto ldx = [&](int t){ return *reinterpret_cast<const float2*>(seq + t*BATCH*2 + b*2); };
  auto lde = [&](int t){ return noise[t*BATCH*HID + b*HID + jl]; };

  float z_prev, ae_c;
  float2 x0v, x1v;

  { // t = 0: first_inference + KL vs unit prior (accumulated in registers)
    float w0 = bload(prm.p[2],      jl, act, S2P);
    float w1 = bload(prm.p[2], 10 + jl, act, S2P);
    float bb = bload(prm.p[3], jl, act, S2P);
    float f_h[16], f_mu[16], f_sg[16];
    loadrot<10,10>(f_h,  prm.p[4], j, j, act, S2P);  float fb_h  = bload(prm.p[5], jl, act, S2P);
    loadrot<10,10>(f_mu, prm.p[6], j, j, act, S2P);  float fb_mu = bload(prm.p[7], jl, act, S2P);
    loadrot<10,10>(f_sg, prm.p[8], j, j, act, SNP);  float fb_sg = bload(prm.p[9], jl, act, SNP);
    x0v = ldx(0);
    float eps = lde(0);
    float h0 = ftanh2(fmaf(x0v.x, w0, fmaf(x0v.y, w1, bb)));
    float r0[16]; ROT16(r0, h0);
    float h1 = ftanh2(dot16(r0, f_h, fb_h));
    float r1[16]; ROT16(r1, h1);
    float mu = ftanh2(dot16(r1, f_mu, fb_mu));
    float sg = fsigm2(dot16(r1, f_sg, fb_sg)) + 0.001f;
    if (act){
      LL += sg + mu*mu;
      L2 -= __log2f(sg);
    }
    z_prev = fmaf(sg, eps, mu);
  }

  { // ae prologue for t=1
    x1v = ldx(1);
    float e1 = ftanh2(fmaf(x1v.x, w_ii0, fmaf(x1v.y, w_ii1, b_in_in)));
    float re1[16]; ROT16(re1, e1);
    v2f wtmp[16];
    #pragma unroll
    for (int k=0;k<16;k++) wtmp[k]=wez[k];
    ae_c = dot16x(re1, wtmp, b_in_j);
  }

  // step t: consumes xa=x(t+1) (e-stage), ec=eps(t), xll=x(t-1) (GLL of gen(t-1))
  auto step = [&](int t, float2 xa, float ec, float2 xll){
    // e-stage for t+1 + paired rotation of z(t-1)
    float e = ftanh2(fmaf(xa.x, w_ii0, fmaf(xa.y, w_ii1, b_in_in)));
    v2f rez[16]; ROTP(rez, e, z_prev);
    v2f d1 = dotp16(rez, wez, (v2f){b_in_j, 0.f});

    // ---- generator(t-1) off rez.y (independent of this step's chain) ----
    float g1 = fmaxf(dot16y(rez, wg1, bg1), 0.f);
    float rg1[16]; ROT16(rg1, g1);
    float g2 = fmaxf(dot16(rg1, wg2, bg2), 0.f);
    float rg2[16]; ROT16(rg2, g2);
    float ygo = dot16(rg2, wgo, bgo);
    float tgo = 1.f + ex2(ygo);          // 1/sigmoid (pre-rcp)
    float tpl = rotk<14>(tgo);           // lane0<-lane2 (1/s0), lane1<-lane3 (1/s1)
    if (j < 2){
      float m = frcp(tgo);
      out[(t-1)*(BATCH*2) + b*2 + j] = m;
      float xd = (j==0) ? xll.x : xll.y;
      float dd = xd - m;
      LL -= dd*dd*tpl;                   // -= d^2 / s
      L2 += __log2f(tpl);                // += log2(1/s) = -log2(s), with B-sign folded
    }

    // ---- transition prior(t) off rez.y (independent) ----
    float th = ftanh2(dot16y(rez, wth, bth));
    float rth[16]; ROT16(rth, th);
    float prmu = ftanh2(dot16(rth, wtmu, btmu));
    float prsg = ftanh2(dot16(rth, wtsg, btsg));

    // ---- serial inference chain ----
    float hj = ftanh2(ae_c + d1.y);
    float rhj[16]; ROT16(rhj, hj);
    float hi = ftanh2(dot16(rhj, w_h, b_in_h));
    float rhi[16]; ROT16(rhi, hi);
    v2f hh[16];
    #pragma unroll
    for (int k=0;k<16;k++) hh[k] = (v2f){rhi[k], rhi[k]};
    v2f d2 = dotp16(hh, wmsg, bmsg);
    float q_mu = ftanh2(d2.x);
    float q_sg = fsigm2(d2.y) + 0.001f;
    float z = fmaf(q_sg, ec, q_mu);

    // ---- KLD(t) ----
    if (act){
      float dmu = prmu - q_mu;
      float rp  = frcp(prsg);
      LL += (q_sg + dmu*dmu)*rp;
      L2 += __log2f(prsg) - __log2f(q_sg);
    }
    z_prev = z;
    ae_c = d1.x;
  };

  // queues: xq = x(2..5) for e-stage; eq = eps(1..4); xc = lagged x(0),x(1) for GLL
  float2 xq0=ldx(2), xq1=ldx(3), xq2=ldx(4), xq3=ldx(5);
  float  eq0=lde(1), eq1=lde(2), eq2=lde(3), eq3=lde(4);
  float2 xc0=x0v, xc1=x1v;

  for (int bt = 0; bt < 62; ++bt){
    const int base = 4*bt;               // steps base+1 .. base+4
    float2 xn0=ldx(base+6), xn1=ldx(base+7), xn2=ldx(base+8), xn3=ldx(base+9);
    float  en0=lde(base+5), en1=lde(base+6), en2=lde(base+7), en3=lde(base+8);
    step(base+1, xq0, eq0, xc0);
    step(base+2, xq1, eq1, xc1);
    step(base+3, xq2, eq2, xq0);
    step(base+4, xq3, eq3, xq1);
    xc0=xq2; xc1=xq3;
    xq0=xn0; xq1=xn1; xq2=xn2; xq3=xn3;
    eq0=en0; eq1=en1; eq2=en2; eq3=en3;
  }
  // tail: queues hold x(250..253), eps(249..252); xc0=x(248), xc1=x(249)
  step(249, xq0, eq0, xc0);
  step(250, xq1, eq1, xc1);
  step(251, xq2, eq2, xq0);
  step(252, xq3, eq3, xq1);
  float2 xA=ldx(254), xB=ldx(255);
  float  eA=lde(253), eB=lde(254), eC=lde(255);
  step(253, xA, eA, xq2);
  step(254, xB, eB, xq3);
  step(255, xB, eC, xA);

  { // epilogue: generator(255) from z(255), GLL with x(255)
    float rzf[16]; ROT16(rzf, z_prev);
    float g1 = fmaxf(dot16(rzf, wg1, bg1), 0.f);
    float rg1[16]; ROT16(rg1, g1);
    float g2 = fmaxf(dot16(rg1, wg2, bg2), 0.f);
    float rg2[16]; ROT16(rg2, g2);
    float ygo = dot16(rg2, wgo, bgo);
    float tgo = 1.f + ex2(ygo);
    float tpl = rotk<14>(tgo);
    if (j < 2){
      float m = frcp(tgo);
      out[255*(BATCH*2) + b*2 + j] = m;
      float xd = (j==0) ? xB.x : xB.y;
      float dd = xd - m;
      LL -= dd*dd*tpl;
      L2 += __log2f(tpl);
    }
  }

  // final per-chain loss: S = sum_lanes(LL + ln2*L2); out = -S/512 + 5 + log(pi)
  float tot = fmaf(LN2, L2, LL);
  tot += xor16<1>(tot); tot += xor16<2>(tot); tot += xor16<4>(tot); tot += xor16<8>(tot);
  if (j == 0)
    out[T_STEPS*BATCH*2 + b] = -tot*(1.0f/512.0f) + 5.0f + LOGPI;
}

extern "C" void kernel_launch(void* const* d_in, const int* in_sizes, int n_in,
                              void* d_out, int out_size, void* d_ws, size_t ws_size,
                              hipStream_t stream) {
  P34 prm;
  for (int i = 0; i < 34; ++i) prm.p[i] = (const float*)d_in[i];
  prm.ws  = (float*)d_ws;   // unused
  prm.out = (float*)d_out;
  hipLaunchKernelGGL(k1_fused, dim3(512), dim3(64), 0, stream, prm);
}

// Round 11
// 183.505 us; speedup vs baseline: 1.2596x; 1.2596x over previous
//
#include <hip/hip_runtime.h>
#include <math.h>

#define T_STEPS 256
#define BATCH   2048
#define HID     10

#define S2P  2.8853900817779268f   // 2/ln2
#define SNP -1.4426950408889634f   // -1/ln2
#define LN2  0.6931471805599453f
#define LOGPI 1.1447298858494002f

typedef float v2f __attribute__((ext_vector_type(2)));

__device__ __forceinline__ float frcp(float x){ return __builtin_amdgcn_rcpf(x); }
__device__ __forceinline__ float ex2 (float x){ return __builtin_amdgcn_exp2f(x); }
__device__ __forceinline__ float ftanh2(float y){ return 1.f - 2.f*frcp(1.f + ex2(y)); }
__device__ __forceinline__ float fsigm2(float y){ return frcp(1.f + ex2(y)); }

// DPP row rotate-right by K within each 16-lane row: result[lane j] = src[(j-K)&15]
template<int K> __device__ __forceinline__ float rotk(float x){
  return __int_as_float(__builtin_amdgcn_update_dpp(
      0, __float_as_int(x), 0x120 + K, 0xF, 0xF, false));
}
#define ROT16(r, v) do{ float _v=(v); r[0]=_v; \
  r[1]=rotk<1>(_v);  r[2]=rotk<2>(_v);  r[3]=rotk<3>(_v);  r[4]=rotk<4>(_v);  \
  r[5]=rotk<5>(_v);  r[6]=rotk<6>(_v);  r[7]=rotk<7>(_v);  r[8]=rotk<8>(_v);  \
  r[9]=rotk<9>(_v);  r[10]=rotk<10>(_v);r[11]=rotk<11>(_v);r[12]=rotk<12>(_v);\
  r[13]=rotk<13>(_v);r[14]=rotk<14>(_v);r[15]=rotk<15>(_v); }while(0)

__device__ __forceinline__ float dot16(const float* r, const float* w, float bias){
  float a0 = fmaf(r[0], w[0], bias);
  float a1 = r[1]*w[1];
  float a2 = r[2]*w[2];
  float a3 = r[3]*w[3];
  #pragma unroll
  for (int k=4;k<16;k+=4){
    a0 = fmaf(r[k  ], w[k  ], a0);
    a1 = fmaf(r[k+1], w[k+1], a1);
    a2 = fmaf(r[k+2], w[k+2], a2);
    a3 = fmaf(r[k+3], w[k+3], a3);
  }
  return (a0+a1)+(a2+a3);
}
__device__ __forceinline__ v2f dotp16(const v2f* r, const v2f* w, v2f init){
  v2f a0 = __builtin_elementwise_fma(r[0], w[0], init);
  v2f a1 = r[1]*w[1];
  v2f a2 = r[2]*w[2];
  v2f a3 = r[3]*w[3];
  #pragma unroll
  for (int k=4;k<16;k+=4){
    a0 = __builtin_elementwise_fma(r[k  ], w[k  ], a0);
    a1 = __builtin_elementwise_fma(r[k+1], w[k+1], a1);
    a2 = __builtin_elementwise_fma(r[k+2], w[k+2], a2);
    a3 = __builtin_elementwise_fma(r[k+3], w[k+3], a3);
  }
  return (a0+a1)+(a2+a3);
}

template<int NROW, int NCOL>
__device__ __forceinline__ void loadrot(float* dst, const float* W, int j, int col,
                                        bool colok, float scale){
  int colc = colok ? col : 0;
  #pragma unroll
  for (int k=0;k<16;k++){
    int i = (j - k) & 15;
    bool v = colok && (i < NROW);
    int ic = v ? i : 0;
    float w = W[ic*NCOL + colc];
    dst[k] = v ? scale*w : 0.f;
  }
}
__device__ __forceinline__ float bload(const float* p, int idx, bool ok, float scale){
  float t = p[ok ? idx : 0];
  return ok ? scale*t : 0.f;
}
template<int X> __device__ __forceinline__ float xor16(float x){
  return __int_as_float(__builtin_amdgcn_ds_swizzle(__float_as_int(x), (X<<10)|0x1f));
}

struct P34 { const float* p[34]; float* out; };

// ===== fused producer/consumer kernel: 2 waves per block, 4 chains per block =====
// wave0 (lanes 0-63 of wave 0): serial inference chain -> z,q into LDS
// wave1: e-stage (ae for t+1), generator+GLL, transition+KLD, loss accumulation
__global__ __attribute__((amdgpu_flat_work_group_size(128, 128), amdgpu_waves_per_eu(1, 1)))
void k_fused(P34 prm)
{
  __shared__ float s_ae[2][64];   // ae(t) buffered by t&1
  __shared__ float s_z [2][64];
  __shared__ float s_qm[2][64];
  __shared__ float s_qs[2][64];
  __shared__ float s_t0[4];       // wave0's t=0 KL contribution per group

  const int tx   = threadIdx.x;
  const int wid  = tx >> 6;
  const int lane = tx & 63;
  const int j    = lane & 15;
  const int grp  = lane >> 4;
  const int b    = blockIdx.x*4 + grp;
  const bool act = (j < HID);
  const int  jl  = act ? j : 0;

  const float* __restrict__ seq   = prm.p[0];
  const float* __restrict__ noise = prm.p[1];
  float* __restrict__ out = prm.out;

  if (wid == 0){
    // ================= wave 0: serial inference chain =================
    float w_jz[16]; loadrot<10,10>(w_jz, prm.p[12] + 100, j, j, act, S2P);
    float w_h [16]; loadrot<10,10>(w_h,  prm.p[14],       j, j, act, S2P);
    float tmu [16]; loadrot<10,10>(tmu,  prm.p[16],       j, j, act, S2P);
    float tsg [16]; loadrot<10,10>(tsg,  prm.p[18],       j, j, act, SNP);
    v2f wmsg[16];
    #pragma unroll
    for (int k=0;k<16;k++) wmsg[k] = (v2f){tmu[k], tsg[k]};
    float b_in_h  = bload(prm.p[15], jl, act, S2P);
    float b_in_mu = bload(prm.p[17], jl, act, S2P);
    float b_in_sg = bload(prm.p[19], jl, act, SNP);
    const v2f bmsg = (v2f){b_in_mu, b_in_sg};

    auto lde = [&](int t){ return noise[t*BATCH*HID + b*HID + jl]; };

    float z_prev;
    { // t = 0: first_inference + KL vs unit prior
      float w0 = bload(prm.p[2],      jl, act, S2P);
      float w1 = bload(prm.p[2], 10 + jl, act, S2P);
      float bb = bload(prm.p[3], jl, act, S2P);
      float f_h[16], f_mu[16], f_sg[16];
      loadrot<10,10>(f_h,  prm.p[4], j, j, act, S2P);  float fb_h  = bload(prm.p[5], jl, act, S2P);
      loadrot<10,10>(f_mu, prm.p[6], j, j, act, S2P);  float fb_mu = bload(prm.p[7], jl, act, S2P);
      loadrot<10,10>(f_sg, prm.p[8], j, j, act, SNP);  float fb_sg = bload(prm.p[9], jl, act, SNP);
      float2 x0 = *reinterpret_cast<const float2*>(seq + b*2);
      float eps = lde(0);
      float h0 = ftanh2(fmaf(x0.x, w0, fmaf(x0.y, w1, bb)));
      float r0[16]; ROT16(r0, h0);
      float h1 = ftanh2(dot16(r0, f_h, fb_h));
      float r1[16]; ROT16(r1, h1);
      float mu = ftanh2(dot16(r1, f_mu, fb_mu));
      float sg = fsigm2(dot16(r1, f_sg, fb_sg)) + 0.001f;
      float term = act ? (sg + mu*mu - __logf(sg)) : 0.f;   // 2x-KL units
      term += xor16<1>(term); term += xor16<2>(term); term += xor16<4>(term); term += xor16<8>(term);
      if (j == 0) s_t0[grp] = term;
      z_prev = fmaf(sg, eps, mu);
      s_z[0][lane] = z_prev;
    }
    float eq0 = lde(1), eq1 = lde(2);
    __syncthreads();                        // prologue barrier

    auto w0step = [&](int s, float ec){
      float aev = s_ae[s&1][lane];          // ds_read; latency covered by ROT/dot below
      float rz[16]; ROT16(rz, z_prev);
      float dz = dot16(rz, w_jz, 0.f);
      float hj = ftanh2(aev + dz);
      float rhj[16]; ROT16(rhj, hj);
      float hi = ftanh2(dot16(rhj, w_h, b_in_h));
      float rhi[16]; ROT16(rhi, hi);
      v2f hh[16];
      #pragma unroll
      for (int k=0;k<16;k++) hh[k] = (v2f){rhi[k], rhi[k]};
      v2f d2 = dotp16(hh, wmsg, bmsg);
      float q_mu = ftanh2(d2.x);
      float q_sg = fsigm2(d2.y) + 0.001f;
      float z = fmaf(q_sg, ec, q_mu);
      int buf = s & 1;
      s_z [buf][lane] = z;
      s_qm[buf][lane] = q_mu;
      s_qs[buf][lane] = q_sg;
      z_prev = z;
    };

    for (int s = 1; s <= 253; ++s){
      float en = lde(s+2);
      w0step(s, eq0);
      eq0 = eq1; eq1 = en;
      __syncthreads();
    }
    w0step(254, eq0); eq0 = eq1; __syncthreads();
    w0step(255, eq0);            __syncthreads();
    // wave0 done (wave1 epilogue reads after the final barrier above)
  } else {
    // ================= wave 1: e-stage + generator + transition/KLD + loss =================
    float w_ii0   = bload(prm.p[10],      jl, act, S2P);
    float w_ii1   = bload(prm.p[10], 10 + jl, act, S2P);
    float b_in_in = bload(prm.p[11], jl, act, S2P);
    float w_je[16]; loadrot<10,10>(w_je, prm.p[12], j, j, act, S2P);
    float b_in_j  = bload(prm.p[13], jl, act, S2P);

    float wg1[16]; loadrot<10,10>(wg1, prm.p[26], j, j, act, 1.f);
    float bg1 = bload(prm.p[27], jl, act, 1.f);
    float wg2[16]; loadrot<10,10>(wg2, prm.p[28], j, j, act, 1.f);
    float bg2 = bload(prm.p[29], jl, act, 1.f);
    const bool isd = (j < 4);
    const float* Wgo = (j < 2) ? prm.p[30] : prm.p[32];
    const float* Bgo = (j < 2) ? prm.p[31] : prm.p[33];
    float wgo[16]; loadrot<10,2>(wgo, Wgo, j, j & 1, isd, SNP);
    float bgo = bload(Bgo, j & 1, isd, SNP);

    float wth [16]; loadrot<10,10>(wth,  prm.p[20], j, j, act, S2P);
    float bth  = bload(prm.p[21], jl, act, S2P);
    float wtmu[16]; loadrot<10,10>(wtmu, prm.p[22], j, j, act, S2P);
    float btmu = bload(prm.p[23], jl, act, S2P);
    float wtsg[16]; loadrot<10,10>(wtsg, prm.p[24], j, j, act, S2P);
    float btsg = bload(prm.p[25], jl, act, S2P);

    float LL = 0.f, L2 = 0.f;
    float rz_prev[16];                      // rot of z(s-2)
    #pragma unroll
    for (int k=0;k<16;k++) rz_prev[k] = 0.f;

    auto ldx = [&](int t){ return *reinterpret_cast<const float2*>(seq + t*BATCH*2 + b*2); };

    { // prologue: ae(1) from x(1)
      float2 x1 = ldx(1);
      float e1 = ftanh2(fmaf(x1.x, w_ii0, fmaf(x1.y, w_ii1, b_in_in)));
      float re[16]; ROT16(re, e1);
      s_ae[1][lane] = dot16(re, w_je, b_in_j);
    }
    float2 xh0 = ldx(0), xh1 = ldx(1), xq0 = ldx(2), xq1 = ldx(3);
    __syncthreads();                        // prologue barrier

    // step body; DO_E: compute ae(s+1) from xq0; KL skipped when s==1
    auto w1step = [&](int s, bool do_e){
      int rbuf = (s-1) & 1, wbuf = (s+1) & 1;
      float zl = s_z [rbuf][lane];
      float qm = s_qm[rbuf][lane];
      float qs = s_qs[rbuf][lane];
      if (do_e){
        float e = ftanh2(fmaf(xq0.x, w_ii0, fmaf(xq0.y, w_ii1, b_in_in)));
        float re[16]; ROT16(re, e);
        s_ae[wbuf][lane] = dot16(re, w_je, b_in_j);
      }
      // generator(s-1) from z(s-1)
      float rz[16]; ROT16(rz, zl);
      float g1 = fmaxf(dot16(rz, wg1, bg1), 0.f);
      float rg1[16]; ROT16(rg1, g1);
      float g2 = fmaxf(dot16(rg1, wg2, bg2), 0.f);
      float rg2[16]; ROT16(rg2, g2);
      float ygo = dot16(rg2, wgo, bgo);
      float tgo = 1.f + ex2(ygo);           // 1/sigmoid
      float tpl = rotk<14>(tgo);            // lanes 0,1 <- lanes 2,3 (1/s)
      if (j < 2){
        float m = frcp(tgo);
        out[(s-1)*(BATCH*2) + b*2 + j] = m;
        float xd = (j==0) ? xh0.x : xh0.y;
        float dd = xd - m;
        LL -= dd*dd*tpl;
        L2 += __log2f(tpl);
      }
      // KLD(s-1): prior from z(s-2), q(s-1)
      if (s > 1){
        float th = ftanh2(dot16(rz_prev, wth, bth));
        float rth[16]; ROT16(rth, th);
        float prmu = ftanh2(dot16(rth, wtmu, btmu));
        float prsg = ftanh2(dot16(rth, wtsg, btsg));
        if (act){
          float dmu = prmu - qm;
          float rp  = frcp(prsg);
          LL += (qs + dmu*dmu)*rp;
          L2 += __log2f(prsg) - __log2f(qs);
        }
      }
      #pragma unroll
      for (int k=0;k<16;k++) rz_prev[k] = rz[k];
    };

    for (int s = 1; s <= 252; ++s){
      float2 xn = ldx(s+3);
      w1step(s, true);
      xh0 = xh1; xh1 = xq0; xq0 = xq1; xq1 = xn;
      __syncthreads();
    }
    // s=253: uses xq0=x(254); s=254: xq0=x(255); s=255: no e-stage
    w1step(253, true);  xh0 = xh1; xh1 = xq0; xq0 = xq1; __syncthreads();
    w1step(254, true);  xh0 = xh1; xh1 = xq0;            __syncthreads();
    w1step(255, false); xh0 = xh1;                        __syncthreads();

    { // epilogue: gen(255) + KL(255) from buf1 (z,q at t=255)
      float zl = s_z [1][lane];
      float qm = s_qm[1][lane];
      float qs = s_qs[1][lane];
      float rz[16]; ROT16(rz, zl);
      float g1 = fmaxf(dot16(rz, wg1, bg1), 0.f);
      float rg1[16]; ROT16(rg1, g1);
      float g2 = fmaxf(dot16(rg1, wg2, bg2), 0.f);
      float rg2[16]; ROT16(rg2, g2);
      float ygo = dot16(rg2, wgo, bgo);
      float tgo = 1.f + ex2(ygo);
      float tpl = rotk<14>(tgo);
      if (j < 2){
        float m = frcp(tgo);
        out[255*(BATCH*2) + b*2 + j] = m;
        float xd = (j==0) ? xh0.x : xh0.y;   // xh0 = x(255)
        float dd = xd - m;
        LL -= dd*dd*tpl;
        L2 += __log2f(tpl);
      }
      float th = ftanh2(dot16(rz_prev, wth, bth));   // rz_prev = rot z(254)
      float rth[16]; ROT16(rth, th);
      float prmu = ftanh2(dot16(rth, wtmu, btmu));
      float prsg = ftanh2(dot16(rth, wtsg, btsg));
      if (act){
        float dmu = prmu - qm;
        float rp  = frcp(prsg);
        LL += (qs + dmu*dmu)*rp;
        L2 += __log2f(prsg) - __log2f(qs);
      }
    }

    // final per-chain loss (2x units): out = -S/512 + 5 + log(pi)
    float tot = fmaf(LN2, L2, LL);
    tot += xor16<1>(tot); tot += xor16<2>(tot); tot += xor16<4>(tot); tot += xor16<8>(tot);
    tot += s_t0[grp];
    if (j == 0)
      out[T_STEPS*BATCH*2 + b] = -tot*(1.0f/512.0f) + 5.0f + LOGPI;
  }
}

extern "C" void kernel_launch(void* const* d_in, const int* in_sizes, int n_in,
                              void* d_out, int out_size, void* d_ws, size_t ws_size,
                              hipStream_t stream) {
  P34 prm;
  for (int i = 0; i < 34; ++i) prm.p[i] = (const float*)d_in[i];
  prm.out = (float*)d_out;
  hipLaunchKernelGGL(k_fused, dim3(512), dim3(128), 0, stream, prm);
}

// Round 12
// 143.643 us; speedup vs baseline: 1.6092x; 1.2775x over previous
//
#include <hip/hip_runtime.h>
#include <math.h>

#define T_STEPS 256
#define BATCH   2048
#define HID     10

#define S2P  2.8853900817779268f   // 2/ln2
#define SNP -1.4426950408889634f   // -1/ln2
#define LN2  0.6931471805599453f
#define LOGPI 1.1447298858494002f

typedef float v2f __attribute__((ext_vector_type(2)));

__device__ __forceinline__ float frcp(float x){ return __builtin_amdgcn_rcpf(x); }
__device__ __forceinline__ float ex2 (float x){ return __builtin_amdgcn_exp2f(x); }
__device__ __forceinline__ float ftanh2(float y){ return 1.f - 2.f*frcp(1.f + ex2(y)); }
__device__ __forceinline__ float fsigm2(float y){ return frcp(1.f + ex2(y)); }

template<int K> __device__ __forceinline__ float rotk(float x){
  return __int_as_float(__builtin_amdgcn_update_dpp(
      0, __float_as_int(x), 0x120 + K, 0xF, 0xF, false));
}
#define ROT16(r, v) do{ float _v=(v); r[0]=_v; \
  r[1]=rotk<1>(_v);  r[2]=rotk<2>(_v);  r[3]=rotk<3>(_v);  r[4]=rotk<4>(_v);  \
  r[5]=rotk<5>(_v);  r[6]=rotk<6>(_v);  r[7]=rotk<7>(_v);  r[8]=rotk<8>(_v);  \
  r[9]=rotk<9>(_v);  r[10]=rotk<10>(_v);r[11]=rotk<11>(_v);r[12]=rotk<12>(_v);\
  r[13]=rotk<13>(_v);r[14]=rotk<14>(_v);r[15]=rotk<15>(_v); }while(0)

__device__ __forceinline__ float dot16(const float* r, const float* w, float bias){
  float a0 = fmaf(r[0], w[0], bias);
  float a1 = r[1]*w[1];
  float a2 = r[2]*w[2];
  float a3 = r[3]*w[3];
  #pragma unroll
  for (int k=4;k<16;k+=4){
    a0 = fmaf(r[k  ], w[k  ], a0);
    a1 = fmaf(r[k+1], w[k+1], a1);
    a2 = fmaf(r[k+2], w[k+2], a2);
    a3 = fmaf(r[k+3], w[k+3], a3);
  }
  return (a0+a1)+(a2+a3);
}
__device__ __forceinline__ v2f dotp16s(const float* r, const v2f* w, v2f init){
  // packed dual dot with a SHARED scalar input vector (splat via same-reg operands)
  v2f a0 = __builtin_elementwise_fma((v2f){r[0],r[0]}, w[0], init);
  v2f a1 = (v2f){r[1],r[1]}*w[1];
  v2f a2 = (v2f){r[2],r[2]}*w[2];
  v2f a3 = (v2f){r[3],r[3]}*w[3];
  #pragma unroll
  for (int k=4;k<16;k+=4){
    a0 = __builtin_elementwise_fma((v2f){r[k  ],r[k  ]}, w[k  ], a0);
    a1 = __builtin_elementwise_fma((v2f){r[k+1],r[k+1]}, w[k+1], a1);
    a2 = __builtin_elementwise_fma((v2f){r[k+2],r[k+2]}, w[k+2], a2);
    a3 = __builtin_elementwise_fma((v2f){r[k+3],r[k+3]}, w[k+3], a3);
  }
  return (a0+a1)+(a2+a3);
}

template<int NROW, int NCOL>
__device__ __forceinline__ void loadrot(float* dst, const float* W, int j, int col,
                                        bool colok, float scale){
  int colc = colok ? col : 0;
  #pragma unroll
  for (int k=0;k<16;k++){
    int i = (j - k) & 15;
    bool v = colok && (i < NROW);
    int ic = v ? i : 0;
    float w = W[ic*NCOL + colc];
    dst[k] = v ? scale*w : 0.f;
  }
}
__device__ __forceinline__ float bload(const float* p, int idx, bool ok, float scale){
  float t = p[ok ? idx : 0];
  return ok ? scale*t : 0.f;
}
template<int X> __device__ __forceinline__ float xor16(float x){
  return __int_as_float(__builtin_amdgcn_ds_swizzle(__float_as_int(x), (X<<10)|0x1f));
}

struct P34 { const float* p[34]; float* out; };

// 2 waves/block, 4 chains/block.
// wave0: serial chain + transition-prior + KLD (all z-side work, KLD fully local)
// wave1: e-stage (ae for t+1) + generator + GLL + output stores
__global__ __attribute__((amdgpu_flat_work_group_size(128, 128), amdgpu_waves_per_eu(1, 1)))
void k_fused(P34 prm)
{
  __shared__ float s_ae[2][64];
  __shared__ float s_z [2][64];
  __shared__ float s_t0[4];

  const int tx   = threadIdx.x;
  const int wid  = tx >> 6;
  const int lane = tx & 63;
  const int j    = lane & 15;
  const int grp  = lane >> 4;
  const int b    = blockIdx.x*4 + grp;
  const bool act = (j < HID);
  const int  jl  = act ? j : 0;

  const float* __restrict__ seq   = prm.p[0];
  const float* __restrict__ noise = prm.p[1];
  float* __restrict__ out = prm.out;

  if (wid == 0){
    // =============== wave 0 ===============
    float w_jz[16]; loadrot<10,10>(w_jz, prm.p[12] + 100, j, j, act, S2P);
    float w_h [16]; loadrot<10,10>(w_h,  prm.p[14],       j, j, act, S2P);
    float tmu [16]; loadrot<10,10>(tmu,  prm.p[16],       j, j, act, S2P);
    float tsg [16]; loadrot<10,10>(tsg,  prm.p[18],       j, j, act, SNP);
    v2f wmsg[16];
    #pragma unroll
    for (int k=0;k<16;k++) wmsg[k] = (v2f){tmu[k], tsg[k]};
    float b_in_h  = bload(prm.p[15], jl, act, S2P);
    const v2f bmsg = (v2f){bload(prm.p[17], jl, act, S2P), bload(prm.p[19], jl, act, SNP)};
    // transition (prior) weights
    float wth [16]; loadrot<10,10>(wth,  prm.p[20], j, j, act, S2P);
    float bth  = bload(prm.p[21], jl, act, S2P);
    float ttmu[16]; loadrot<10,10>(ttmu, prm.p[22], j, j, act, S2P);
    float ttsg[16]; loadrot<10,10>(ttsg, prm.p[24], j, j, act, S2P);
    v2f wpr[16];
    #pragma unroll
    for (int k=0;k<16;k++) wpr[k] = (v2f){ttmu[k], ttsg[k]};
    const v2f bpr = (v2f){bload(prm.p[23], jl, act, S2P), bload(prm.p[25], jl, act, S2P)};

    float LL = 0.f, L2 = 0.f;
    auto lde = [&](int t){ return noise[t*BATCH*HID + b*HID + jl]; };

    float z_prev;
    { // t=0: first_inference + KL vs unit prior
      float w0 = bload(prm.p[2],      jl, act, S2P);
      float w1 = bload(prm.p[2], 10 + jl, act, S2P);
      float bb = bload(prm.p[3], jl, act, S2P);
      float f_h[16], f_mu[16], f_sg[16];
      loadrot<10,10>(f_h,  prm.p[4], j, j, act, S2P);  float fb_h  = bload(prm.p[5], jl, act, S2P);
      loadrot<10,10>(f_mu, prm.p[6], j, j, act, S2P);  float fb_mu = bload(prm.p[7], jl, act, S2P);
      loadrot<10,10>(f_sg, prm.p[8], j, j, act, SNP);  float fb_sg = bload(prm.p[9], jl, act, SNP);
      float2 x0 = *reinterpret_cast<const float2*>(seq + b*2);
      float eps = lde(0);
      float h0 = ftanh2(fmaf(x0.x, w0, fmaf(x0.y, w1, bb)));
      float r0[16]; ROT16(r0, h0);
      float h1 = ftanh2(dot16(r0, f_h, fb_h));
      float r1[16]; ROT16(r1, h1);
      float mu = ftanh2(dot16(r1, f_mu, fb_mu));
      float sg = fsigm2(dot16(r1, f_sg, fb_sg)) + 0.001f;
      if (act){ LL += sg + mu*mu; L2 -= __log2f(sg); }
      z_prev = fmaf(sg, eps, mu);
      s_z[0][lane] = z_prev;
    }
    float e0=lde(1), e1=lde(2), e2=lde(3), e3=lde(4);
    __syncthreads();                                   // barrier #1

    auto w0step = [&](const float* aeb, float* zb, float ec){
      float aev = aeb[lane];
      float rz[16]; ROT16(rz, z_prev);
      // serial chain
      float hj = ftanh2(aev + dot16(rz, w_jz, 0.f));
      float rhj[16]; ROT16(rhj, hj);
      float hi = ftanh2(dot16(rhj, w_h, b_in_h));
      float rhi[16]; ROT16(rhi, hi);
      v2f d2 = dotp16s(rhi, wmsg, bmsg);
      float q_mu = ftanh2(d2.x);
      float q_sg = fsigm2(d2.y) + 0.001f;
      float z = fmaf(q_sg, ec, q_mu);
      zb[lane] = z;
      // prior + KLD off rz (independent; fills chain stalls)
      float th = ftanh2(dot16(rz, wth, bth));
      float rth[16]; ROT16(rth, th);
      v2f d3 = dotp16s(rth, wpr, bpr);
      float prmu = ftanh2(d3.x);
      float prsg = ftanh2(d3.y);
      if (act){
        float dmu = prmu - q_mu;
        float rp  = frcp(prsg);
        LL += (q_sg + dmu*dmu)*rp;
        L2 += __log2f(prsg) - __log2f(q_sg);
      }
      z_prev = z;
    };

    for (int p = 0; p < 125; ++p){                     // s = 2p+1, 2p+2  (1..250)
      int s = 2*p + 1;
      float n0 = lde(s+4), n1 = lde(s+5);
      w0step(s_ae[1], s_z[1], e0); __syncthreads();
      w0step(s_ae[0], s_z[0], e1); __syncthreads();
      e0=e2; e1=e3; e2=n0; e3=n1;
    }
    // peel s=251..255 (e0..e3 = eps(251..254))
    float e255 = lde(255);
    w0step(s_ae[1], s_z[1], e0);   __syncthreads();    // 251
    w0step(s_ae[0], s_z[0], e1);   __syncthreads();    // 252
    w0step(s_ae[1], s_z[1], e2);   __syncthreads();    // 253
    w0step(s_ae[0], s_z[0], e3);   __syncthreads();    // 254
    w0step(s_ae[1], s_z[1], e255); __syncthreads();    // 255

    float tot = fmaf(LN2, L2, LL);
    tot += xor16<1>(tot); tot += xor16<2>(tot); tot += xor16<4>(tot); tot += xor16<8>(tot);
    if (j == 0) s_t0[grp] = tot;
    __syncthreads();                                   // final barrier
  } else {
    // =============== wave 1 ===============
    float w_ii0   = bload(prm.p[10],      jl, act, S2P);
    float w_ii1   = bload(prm.p[10], 10 + jl, act, S2P);
    float b_in_in = bload(prm.p[11], jl, act, S2P);
    float w_je[16]; loadrot<10,10>(w_je, prm.p[12], j, j, act, S2P);
    float b_in_j  = bload(prm.p[13], jl, act, S2P);

    float wg1[16]; loadrot<10,10>(wg1, prm.p[26], j, j, act, 1.f);
    float bg1 = bload(prm.p[27], jl, act, 1.f);
    float wg2[16]; loadrot<10,10>(wg2, prm.p[28], j, j, act, 1.f);
    float bg2 = bload(prm.p[29], jl, act, 1.f);
    const bool isd = (j < 4);
    const float* Wgo = (j < 2) ? prm.p[30] : prm.p[32];
    const float* Bgo = (j < 2) ? prm.p[31] : prm.p[33];
    float wgo[16]; loadrot<10,2>(wgo, Wgo, j, j & 1, isd, SNP);
    float bgo = bload(Bgo, j & 1, isd, SNP);

    float LL = 0.f, L2 = 0.f;
    auto ldx = [&](int t){ return *reinterpret_cast<const float2*>(seq + t*BATCH*2 + b*2); };

    { // prologue: ae(1)
      float2 x1 = ldx(1);
      float e = ftanh2(fmaf(x1.x, w_ii0, fmaf(x1.y, w_ii1, b_in_in)));
      float re[16]; ROT16(re, e);
      s_ae[1][lane] = dot16(re, w_je, b_in_j);
    }
    float2 xA = ldx(0), xB = ldx(1), xC = ldx(2), xD = ldx(3);
    __syncthreads();                                   // barrier #1

    // iter s: gen(s-1) from z(s-1) + GLL(x(s-1)); e-stage ae(s+1) from x(s+1)
    auto w1step = [&](const float* zb, float* aeb, float2 xgll, float2 xe, int tG, bool do_e){
      float zl = zb[lane];
      if (do_e){
        float e = ftanh2(fmaf(xe.x, w_ii0, fmaf(xe.y, w_ii1, b_in_in)));
        float re[16]; ROT16(re, e);
        aeb[lane] = dot16(re, w_je, b_in_j);
      }
      float rz[16]; ROT16(rz, zl);
      float g1 = fmaxf(dot16(rz, wg1, bg1), 0.f);
      float rg1[16]; ROT16(rg1, g1);
      float g2 = fmaxf(dot16(rg1, wg2, bg2), 0.f);
      float rg2[16]; ROT16(rg2, g2);
      float ygo = dot16(rg2, wgo, bgo);
      float tgo = 1.f + ex2(ygo);                      // 1/sigmoid
      float tpl = rotk<14>(tgo);                       // lanes 0,1 <- 2,3
      if (j < 2){
        float m = frcp(tgo);
        out[tG*(BATCH*2) + b*2 + j] = m;
        float dd = ((j==0) ? xgll.x : xgll.y) - m;
        LL -= dd*dd*tpl;
        L2 += __log2f(tpl);
      }
    };

    for (int p = 0; p < 125; ++p){                     // s = 2p+1, 2p+2
      int s = 2*p + 1;
      float2 n0 = ldx(s+3), n1 = ldx(s+4);
      w1step(s_z[0], s_ae[0], xA, xC, s-1, true); __syncthreads();
      w1step(s_z[1], s_ae[1], xB, xD, s,   true); __syncthreads();
      xA=xC; xB=xD; xC=n0; xD=n1;
    }
    // peel s=251..255 (xA..xD = x(250..253))
    float2 x254 = ldx(254), x255 = ldx(255);
    w1step(s_z[0], s_ae[0], xA, xC,   250, true);  __syncthreads();   // 251
    w1step(s_z[1], s_ae[1], xB, xD,   251, true);  __syncthreads();   // 252
    w1step(s_z[0], s_ae[0], xC, x254, 252, true);  __syncthreads();   // 253
    w1step(s_z[1], s_ae[1], xD, x255, 253, true);  __syncthreads();   // 254
    w1step(s_z[0], s_ae[0], x254, x255, 254, false); __syncthreads(); // 255
    // epilogue: gen(255) from z(255) (in s_z[1]); GLL with x(255)
    w1step(s_z[1], s_ae[1], x255, x255, 255, false);

    float tot = fmaf(LN2, L2, LL);
    tot += xor16<1>(tot); tot += xor16<2>(tot); tot += xor16<4>(tot); tot += xor16<8>(tot);
    __syncthreads();                                   // final barrier
    if (j == 0)
      out[T_STEPS*BATCH*2 + b] = -(tot + s_t0[grp])*(1.0f/512.0f) + 5.0f + LOGPI;
  }
}

extern "C" void kernel_launch(void* const* d_in, const int* in_sizes, int n_in,
                              void* d_out, int out_size, void* d_ws, size_t ws_size,
                              hipStream_t stream) {
  P34 prm;
  for (int i = 0; i < 34; ++i) prm.p[i] = (const float*)d_in[i];
  prm.out = (float*)d_out;
  hipLaunchKernelGGL(k_fused, dim3(512), dim3(128), 0, stream, prm);
}